// Round 11
// baseline (182.170 us; speedup 1.0000x reference)
//
#include <hip/hip_runtime.h>
#include <math.h>

// ============================================================================
// Sizes (fixed): N=2, C=64, Hax=56, W=56 -> B=112, H=56, OUT=64, N_HASHES=4,
// CHUNK=25, GROUPS=8, GP=8, hash_buckets=2, padding=19, K=3, qkv ch=96.
// Inputs fp32; OUTPUT FP32; stable argsort (established R8-R11).
// R24: 142.3us, k3=49.4 @ VGPR40 (rolled main loop = spill brake, confirmed).
// R25: k3 K-MERGE: grid (112,4,3)->(112,4); one block does all 3 k's.
//   Removes the 3x-redundant gather+normalize staging (each k-block staged
//   identical Wc/Vb). To fit LDS: nrm[8][3][25] replaces raw WbK; wbr
//   reconstructed = (WcF - 0.1we)*nrm (numerics validated R18/R19; spill
//   there was the full-unroll rule, main stays rolled). weL prescaled 0.1x
//   replaces relL; ibL aliases DIT. LDS 56.0KB -> 2 blocks/CU; 448 blocks =
//   single fully-resident round (no tail; was 1.75 rounds).
//   Signature prediction: FETCH 1.3MB -> ~0.5MB (qkv gathered 1x not 3x).
//
// ws layout (float slots):
//   qkv : [112][5376]   off 0
//   bsb : [112][2400]   off 602112
//   Rb  : [112][38400]  off 870912  (xT[2][56][56][64] aliases this pre-k3)
//   idx : [112][224]    off 5171712 (int)
// ============================================================================

#define EPSN 5e-5f
#define INV_EPSN 20000.0f
#define LOG2E 1.4426950408889634f
#define LN2   0.6931471805599453f

__device__ __forceinline__ float dot4(const float4 a, const float4 b) {
    return a.x * b.x + a.y * b.y + a.z * b.z + a.w * b.w;
}
__device__ __forceinline__ void fma4(float4& a, float s, const float4 v) {
    a.x += s * v.x; a.y += s * v.y; a.z += s * v.z; a.w += s * v.w;
}

// ---------------- K0: x[n][c][h][w] -> xT[n][h][w][c] (LDS transpose) ------
__global__ __launch_bounds__(256) void k0_xT(
        const float* __restrict__ x, float* __restrict__ xT) {
    __shared__ float T[64][57];                 // pad 57: conflict-free read
    const int n = blockIdx.x, h = blockIdx.y, tid = threadIdx.x;
    const float* xb = x + n * 200704 + h * 56;
    #pragma unroll 7
    for (int i = tid; i < 3584; i += 256) {     // lanes: consecutive w
        int c = i / 56, w = i % 56;
        T[c][w] = xb[c * 3136 + w];
    }
    __syncthreads();
    float* xo = xT + n * 200704 + h * 3584;
    #pragma unroll 7
    for (int i = tid; i < 3584; i += 256) {     // lanes: consecutive c
        int w = i / 64, c = i % 64;
        xo[w * 64 + c] = T[c][w];
    }
}

// ---------------- K12: qkv GEMM + BN + LSH codes + stable argsort ----------
// o-quad x h-pair register tile: 672 tiles, 6 LDS reads per 32 FMA.
__global__ __launch_bounds__(256) void k12_qkv_sort(
        const float* __restrict__ xT, const float* __restrict__ cw,
        const float* __restrict__ gamma, const float* __restrict__ beta,
        const float* __restrict__ rot, float* __restrict__ qkv,
        int* __restrict__ idx_buf) {
    __shared__ float xsT[56 * 68];   // [h][c], pad 64->68
    __shared__ float cws[96 * 64];
    __shared__ float wm[56 * 32];    // w_match[t][f]
    __shared__ float rl[128];
    __shared__ float gs[96], bt[96];
    __shared__ int code[224];
    __shared__ int srt[224];
    const int b = blockIdx.x, n = b / 56, w = b % 56, tid = threadIdx.x;
    const float* xTb = xT + n * 200704 + w * 64;
    #pragma unroll 4
    for (int i = tid; i < 896; i += 256) {      // coalesced float4 rows
        int h = i / 16, cq = i % 16;
        *(float4*)&xsT[h * 68 + cq * 4] =
            *(const float4*)&xTb[h * 3584 + cq * 4];
    }
    #pragma unroll 8
    for (int i = tid; i < 6144; i += 256) cws[i] = cw[i];
    if (tid < 128) rl[tid] = rot[tid];
    if (tid < 96) { gs[tid] = gamma[tid]; bt[tid] = beta[tid]; }
    __syncthreads();
    const float inv_s = 1.0f / sqrtf(1.0f + 1.0e-5f);
    // 672 tiles = 24 o-quads x 28 h-pairs.
    for (int tl = tid; tl < 672; tl += 256) {
        int oq = tl / 28, hp = tl % 28;
        int o0 = oq * 4, h0 = hp * 2;
        float s00 = 0.f, s01 = 0.f, s10 = 0.f, s11 = 0.f;
        float s20 = 0.f, s21 = 0.f, s30 = 0.f, s31 = 0.f;
        #pragma unroll
        for (int cs = 0; cs < 16; ++cs) {
            float4 xv0 = *(const float4*)&xsT[h0 * 68 + cs * 4];
            float4 xv1 = *(const float4*)&xsT[(h0 + 1) * 68 + cs * 4];
            float4 c0 = *(const float4*)&cws[(o0 + 0) * 64 + cs * 4];
            float4 c1 = *(const float4*)&cws[(o0 + 1) * 64 + cs * 4];
            float4 c2 = *(const float4*)&cws[(o0 + 2) * 64 + cs * 4];
            float4 c3 = *(const float4*)&cws[(o0 + 3) * 64 + cs * 4];
            s00 += dot4(xv0, c0); s01 += dot4(xv1, c0);
            s10 += dot4(xv0, c1); s11 += dot4(xv1, c1);
            s20 += dot4(xv0, c2); s21 += dot4(xv1, c2);
            s30 += dot4(xv0, c3); s31 += dot4(xv1, c3);
        }
        #pragma unroll
        for (int qq = 0; qq < 4; ++qq) {
            #pragma unroll
            for (int hh = 0; hh < 2; ++hh) {
                float sv = (qq == 0) ? (hh ? s01 : s00)
                         : (qq == 1) ? (hh ? s11 : s10)
                         : (qq == 2) ? (hh ? s21 : s20)
                                     : (hh ? s31 : s30);
                int o = o0 + qq, h = h0 + hh;
                float val = sv * inv_s * gs[o] + bt[o];
                int j = o * 56 + h;
                qkv[b * 5376 + j] = val;
                int f = j % 96;                  // raw (B,96,56)->(B,56,96)
                if (f < 32) wm[(j / 96) * 32 + f] = val;
            }
        }
    }
    __syncthreads();
    if (tid < 224) {
        int u = tid / 56, t = tid % 56;
        float s = 0.f;
        #pragma unroll 8
        for (int f = 0; f < 32; ++f) s += wm[t * 32 + f] * rl[f * 4 + u];
        code[tid] = ((s < 0.f) ? 1 : 0) + 2 * u;
    }
    __syncthreads();
    if (tid < 224) {
        int c = code[tid], r = 0;
        #pragma unroll 8
        for (int p = 0; p < 224; ++p) {
            int cp = code[p];
            r += (int)((cp < c) | ((cp == c) & (p < tid)));  // stable rank
        }
        srt[r] = tid;
    }
    __syncthreads();
    if (tid < 224) idx_buf[b * 224 + tid] = srt[tid];
}

// ---------------- K3: chunked attention, one block per (b,u), ALL 3 k's ----
// Stage once (gather+normalize+nrm), DI for 3 k's, fold, main x3 k's with
// reconstructed wbr = (WcF - 0.1we)*nrm. Rolled main loop (spill brake).
// LDS 56.0KB -> 2 blocks/CU; 448 blocks = single resident round (no tail).
__global__ __launch_bounds__(512) void k3_attn(
        const float* __restrict__ qkv, const int* __restrict__ idx_buf,
        const float* __restrict__ rel, float* __restrict__ Rb,
        float* __restrict__ bsb) {
    __shared__ __align__(16) float Wc[8][3][25][4];   // normalized, then folded
    __shared__ __align__(16) float Vb[8][3][25][8];
    __shared__ float nrm[8][3][25];                   // |v| per (g,kk,i)
    __shared__ float DIT[3][75][25];                  // di*LOG2E; ibL aliases
    __shared__ __align__(16) float weL[75][4];        // 0.1*we[j]
    __shared__ __align__(16) float veL[600];          // VE[j][0..7]
    int* ibL = (int*)&DIT[0][0][0];
    const int b = blockIdx.x, u = blockIdx.y;
    const int tid = threadIdx.x;
    const float* q = qkv + b * 5376;

    if (tid < 224) ibL[tid] = idx_buf[b * 224 + tid];
    for (int i2 = tid; i2 < 300; i2 += 512) {         // weL (prescaled 0.1x)
        int j = i2 >> 2, c = i2 & 3;
        int roww = (j < 56) ? j : j - 19;
        weL[j][c] = 0.1f * rel[roww * 12 + c];
    }
    #pragma unroll 2
    for (int i2 = tid; i2 < 600; i2 += 512) {         // veL
        int j = i2 >> 3, c = i2 & 7;
        int roww = (j < 56) ? j : j - 19;
        veL[i2] = rel[roww * 12 + 4 + c];
    }
    __syncthreads();

    // Gather + normalize (ONCE for all 3 k's); keep norms for reconstruction.
    #pragma unroll 2
    for (int idx = tid; idx < 600; idx += 512) {
        int i = idx % 25, kk = (idx / 25) % 3, g = idx / 75;
        int p0 = 1200 * g + 300 * u + 100 * kk + 4 * i;
        int h = p0 / 2400, r = p0 % 2400, t = r >> 5, f = r & 31;
        int row = (t < 56) ? t : t - 19;
        int tt = ibL[h * 56 + row] % 56;
        float4 v = *(const float4*)&q[tt * 96 + f];
        float len = fmaxf(sqrtf(dot4(v, v)), EPSN);
        float ni = 1.0f / len;
        v.x *= ni; v.y *= ni; v.z *= ni; v.w *= ni;
        *(float4*)&Wc[g][kk][i][0] = v;
        nrm[g][kk][i] = len;
    }
    #pragma unroll 3
    for (int idx = tid; idx < 1200; idx += 512) {
        int half = idx & 1, fr = idx >> 1;
        int i = fr % 25, kk = (fr / 25) % 3, g = fr / 75;
        int p0 = 2400 * g + 600 * u + 200 * kk + 8 * i + 4 * half;
        int h = p0 / 4800, r = p0 % 4800, t = r >> 6, f = r & 63;
        int row = (t < 56) ? t : t - 19;
        int tt = ibL[h * 56 + row] % 56;
        *(float4*)&Vb[g][kk][i][4 * half] = *(const float4*)&q[tt * 96 + 32 + f];
    }
    __syncthreads();                      // ibL dead; DIT writable

    // DI: 375 threads x 3 k's x 5 j's; wb8 = Wc[g][kq][i]*nrm (reconstruct).
    if (tid < 375) {
        const int i = tid % 25, jg = tid / 25;        // jg 0..14
        #pragma unroll
        for (int kq = 0; kq < 3; ++kq) {
            float4 wb8[8];
            #pragma unroll
            for (int g = 0; g < 8; ++g) {
                float4 t4 = *(const float4*)&Wc[g][kq][i][0];
                float nr = nrm[g][kq][i];
                wb8[g].x = t4.x * nr; wb8[g].y = t4.y * nr;
                wb8[g].z = t4.z * nr; wb8[g].w = t4.w * nr;
            }
            #pragma unroll
            for (int it = 0; it < 5; ++it) {
                int j = jg * 5 + it;
                int ks = (j >= 25) + (j >= 50), jj = j - ks * 25;
                float4 we = *(const float4*)&weL[j][0];   // already 0.1x
                float s2 = 0.f;
                #pragma unroll
                for (int g = 0; g < 8; ++g) {
                    float4 wcn = *(const float4*)&Wc[g][ks][jj][0];
                    float raw = dot4(wb8[g], wcn);
                    float emb = dot4(wb8[g], we);
                    s2 += raw * raw + emb * emb;
                }
                DIT[kq][j][i] = fminf(__builtin_amdgcn_rsqf(s2), INV_EPSN) * LOG2E;
            }
        }
    }
    __syncthreads();

    // Fold 0.1*we into Wc (in place).
    #pragma unroll 2
    for (int idx = tid; idx < 600; idx += 512) {
        int i = idx % 25, kk = (idx / 25) % 3, g = idx / 75;
        float4 we = *(const float4*)&weL[kk * 25 + i][0];
        float4 v = *(const float4*)&Wc[g][kk][i][0];
        v.x += we.x; v.y += we.y; v.z += we.z; v.w += we.w;
        *(float4*)&Wc[g][kk][i][0] = v;
    }
    __syncthreads();

    // Main x3 k's: channel-split lane pairs, rolled j loop (unroll 5).
    if (tid < 400) {
        const int half = tid & 1, gi = tid >> 1;      // gi 0..199
        const int g = gi & 7, i = gi >> 3;
        const int co = 4 * half;
        const float* Wcf = &Wc[g][0][0][0];           // j-contig, stride 4
        const float* Vbf = &Vb[g][0][0][co];          // j-contig, stride 8
        const float* vef = &veL[co];                  // j-contig, stride 8
        #pragma unroll 1
        for (int kq = 0; kq < 3; ++kq) {
            float4 wbr;                               // reconstruct raw w_b
            {
                float4 t4 = *(const float4*)&Wc[g][kq][i][0];   // folded
                float4 wei = *(const float4*)&weL[kq * 25 + i][0];
                float nr = nrm[g][kq][i];
                wbr.x = (t4.x - wei.x) * nr;
                wbr.y = (t4.y - wei.y) * nr;
                wbr.z = (t4.z - wei.z) * nr;
                wbr.w = (t4.w - wei.w) * nr;
            }
            const float* DIf = &DIT[kq][0][i];        // j-contig, stride 25
            float se = 0.f;
            float4 av = {0,0,0,0}, ae = {0,0,0,0};
            #pragma unroll 5
            for (int j = 0; j < 75; ++j) {            // ROLLED: spill brake
                float e = __builtin_amdgcn_exp2f(
                    dot4(wbr, *(const float4*)&Wcf[j * 4]) * DIf[j * 25]);
                se += e;
                fma4(av, e, *(const float4*)&Vbf[j * 8]);
                fma4(ae, e, *(const float4*)&vef[j * 8]);
            }
            if (half == 0)
                bsb[b * 2400 + g * 300 + u * 75 + kq * 25 + i] =
                    __builtin_amdgcn_logf(se) * LN2;  // logsumexp, no shift
            const float rinv = 1.0f / se;
            const float r2 = 0.1f * rinv;             // F_GV1
            av.x *= rinv; av.y *= rinv; av.z *= rinv; av.w *= rinv;
            ae.x *= r2;   ae.y *= r2;   ae.z *= r2;   ae.w *= r2;
            float* rp = Rb + b * 38400 + 4800 * g + 1200 * u + 400 * kq + 16 * i;
            *(float4*)(rp + co) = av;                 // V half
            *(float4*)(rp + 8 + co) = ae;             // VE half
        }
    }
}

// ---------------- K45: channel l2norm + bs-pass + unsort + hash softmax
//                        + transposed FP32 store. Split (b, o-half), 512 thr.
__global__ __launch_bounds__(512) void k45_post(
        const float* __restrict__ Rb, const float* __restrict__ bsb,
        const int* __restrict__ idx_buf, float* __restrict__ out) {
    __shared__ float D[300];
    __shared__ float bsn[300];
    __shared__ float retU[224][32];
    __shared__ float bsU[224];
    __shared__ int idxL[224];
    const int b = blockIdx.x, oh = blockIdx.y, tid = threadIdx.x;
    const int n = b / 56, w = b % 56, o0 = oh * 32;
    const float* R = Rb + b * 38400;
    if (tid < 224) idxL[tid] = idx_buf[b * 224 + tid];
    if (tid < 300) {
        float s = 0.f;
        #pragma unroll 16
        for (int c = 0; c < 128; ++c) { float v = R[c * 300 + tid]; s += v * v; }
        D[tid] = fminf(__builtin_amdgcn_rsqf(s), INV_EPSN);
    }
    if (tid < 300) {
        int u = tid / 75, t = tid % 75;
        float s2 = 0.f, sum = 0.f;
        #pragma unroll
        for (int g = 0; g < 8; ++g) {
            float v = bsb[b * 2400 + g * 300 + u * 75 + t];
            s2 += v * v; sum += v;
        }
        bsn[tid] = sum / fmaxf(sqrtf(s2), EPSN);
    }
    __syncthreads();
    if (tid < 224) {
        int u3 = tid / 56, t = tid % 56;
        bsU[idxL[tid]] = bsn[u3 * 75 + t];
    }
    #pragma unroll 4
    for (int idx = tid; idx < 224 * 32; idx += 512) {
        int p = idx >> 5, oc = idx & 31;
        int o = o0 + oc;
        int u3 = p / 56, t = p % 56;
        int k3 = t / 25, i3 = t % 25;
        int q0 = 9600 * u3 + 3200 * k3 + 128 * i3 + 2 * o;
        float2 rv = *(const float2*)&R[q0];
        int r0 = q0 % 300;                       // q0 even => r0+1 never wraps
        float val = rv.x * D[r0] + rv.y * D[r0 + 1];
        retU[idxL[p]][oc] = val;
    }
    __syncthreads();
    for (int idx = tid; idx < 56 * 32; idx += 512) {
        int h = idx >> 5, oc = idx & 31;
        int o = o0 + oc;
        float b0 = bsU[h], b1 = bsU[56 + h], b2 = bsU[112 + h], b3 = bsU[168 + h];
        float m = fmaxf(fmaxf(b0, b1), fmaxf(b2, b3));
        float e0 = __builtin_amdgcn_exp2f((b0 - m) * LOG2E);
        float e1 = __builtin_amdgcn_exp2f((b1 - m) * LOG2E);
        float e2 = __builtin_amdgcn_exp2f((b2 - m) * LOG2E);
        float e3 = __builtin_amdgcn_exp2f((b3 - m) * LOG2E);
        float ps = e0 + e1 + e2 + e3;
        float val = (retU[h][oc] * e0 + retU[56 + h][oc] * e1 +
                     retU[112 + h][oc] * e2 + retU[168 + h][oc] * e3) / ps;
        out[((n * 64 + o) * 56 + h) * 56 + w] = val;   // (n,o,h,w)
    }
}

extern "C" void kernel_launch(void* const* d_in, const int* in_sizes, int n_in,
                              void* d_out, int out_size, void* d_ws, size_t ws_size,
                              hipStream_t stream) {
    (void)in_sizes; (void)n_in; (void)out_size; (void)ws_size;
    const float* x     = (const float*)d_in[0];
    const float* cw    = (const float*)d_in[1];
    const float* gamma = (const float*)d_in[2];
    const float* beta  = (const float*)d_in[3];
    const float* rel   = (const float*)d_in[4];
    const float* rot   = (const float*)d_in[5];
    float* ws  = (float*)d_ws;
    float* qkv = ws;
    float* bsb = ws + 602112;
    float* Rb  = ws + 870912;
    float* xT  = Rb;                 // aliases Rb; dead once k3 writes Rb
    int*   idx = (int*)(ws + 5171712);

    k0_xT<<<dim3(2, 56), 256, 0, stream>>>(x, xT);
    k12_qkv_sort<<<112, 256, 0, stream>>>(xT, cw, gamma, beta, rot, qkv, idx);
    k3_attn<<<dim3(112, 4), 512, 0, stream>>>(qkv, idx, rel, Rb, bsb);
    k45_post<<<dim3(112, 2), 512, 0, stream>>>(Rb, bsb, idx, (float*)d_out);
}

// Round 12
// 148.761 us; speedup vs baseline: 1.2246x; 1.2246x over previous
//
#include <hip/hip_runtime.h>
#include <math.h>

// ============================================================================
// Sizes (fixed): N=2, C=64, Hax=56, W=56 -> B=112, H=56, OUT=64, N_HASHES=4,
// CHUNK=25, GROUPS=8, GP=8, hash_buckets=2, padding=19, K=3, qkv ch=96.
// Inputs fp32; OUTPUT FP32; stable argsort (established R8-R11).
// R24: 142.3us, k3=49.4 @ VGPR40 (rolled main loop = spill brake, confirmed).
// R25: K-merge grid (112,4), but DI's kq loop had `#pragma unroll` (FULL) ->
//      3x wb8[8] (96 VGPR) live -> VGPR 128 + scratch spill (FETCH 31MB,
//      WRITE 77MB, k3 87us). Same signature as R18/R22.
// R26: single fix: `#pragma unroll 1` on DI kq loop (one wb8[8] live at a
//      time; R24 proved single-kq DI fits in 40 VGPR). Everything else
//      identical to R25. K-merge signature expected: FETCH -> ~0.5MB.
//
// ws layout (float slots):
//   qkv : [112][5376]   off 0
//   bsb : [112][2400]   off 602112
//   Rb  : [112][38400]  off 870912  (xT[2][56][56][64] aliases this pre-k3)
//   idx : [112][224]    off 5171712 (int)
// ============================================================================

#define EPSN 5e-5f
#define INV_EPSN 20000.0f
#define LOG2E 1.4426950408889634f
#define LN2   0.6931471805599453f

__device__ __forceinline__ float dot4(const float4 a, const float4 b) {
    return a.x * b.x + a.y * b.y + a.z * b.z + a.w * b.w;
}
__device__ __forceinline__ void fma4(float4& a, float s, const float4 v) {
    a.x += s * v.x; a.y += s * v.y; a.z += s * v.z; a.w += s * v.w;
}

// ---------------- K0: x[n][c][h][w] -> xT[n][h][w][c] (LDS transpose) ------
__global__ __launch_bounds__(256) void k0_xT(
        const float* __restrict__ x, float* __restrict__ xT) {
    __shared__ float T[64][57];                 // pad 57: conflict-free read
    const int n = blockIdx.x, h = blockIdx.y, tid = threadIdx.x;
    const float* xb = x + n * 200704 + h * 56;
    #pragma unroll 7
    for (int i = tid; i < 3584; i += 256) {     // lanes: consecutive w
        int c = i / 56, w = i % 56;
        T[c][w] = xb[c * 3136 + w];
    }
    __syncthreads();
    float* xo = xT + n * 200704 + h * 3584;
    #pragma unroll 7
    for (int i = tid; i < 3584; i += 256) {     // lanes: consecutive c
        int w = i / 64, c = i % 64;
        xo[w * 64 + c] = T[c][w];
    }
}

// ---------------- K12: qkv GEMM + BN + LSH codes + stable argsort ----------
// o-quad x h-pair register tile: 672 tiles, 6 LDS reads per 32 FMA.
__global__ __launch_bounds__(256) void k12_qkv_sort(
        const float* __restrict__ xT, const float* __restrict__ cw,
        const float* __restrict__ gamma, const float* __restrict__ beta,
        const float* __restrict__ rot, float* __restrict__ qkv,
        int* __restrict__ idx_buf) {
    __shared__ float xsT[56 * 68];   // [h][c], pad 64->68
    __shared__ float cws[96 * 64];
    __shared__ float wm[56 * 32];    // w_match[t][f]
    __shared__ float rl[128];
    __shared__ float gs[96], bt[96];
    __shared__ int code[224];
    __shared__ int srt[224];
    const int b = blockIdx.x, n = b / 56, w = b % 56, tid = threadIdx.x;
    const float* xTb = xT + n * 200704 + w * 64;
    #pragma unroll 4
    for (int i = tid; i < 896; i += 256) {      // coalesced float4 rows
        int h = i / 16, cq = i % 16;
        *(float4*)&xsT[h * 68 + cq * 4] =
            *(const float4*)&xTb[h * 3584 + cq * 4];
    }
    #pragma unroll 8
    for (int i = tid; i < 6144; i += 256) cws[i] = cw[i];
    if (tid < 128) rl[tid] = rot[tid];
    if (tid < 96) { gs[tid] = gamma[tid]; bt[tid] = beta[tid]; }
    __syncthreads();
    const float inv_s = 1.0f / sqrtf(1.0f + 1.0e-5f);
    // 672 tiles = 24 o-quads x 28 h-pairs.
    for (int tl = tid; tl < 672; tl += 256) {
        int oq = tl / 28, hp = tl % 28;
        int o0 = oq * 4, h0 = hp * 2;
        float s00 = 0.f, s01 = 0.f, s10 = 0.f, s11 = 0.f;
        float s20 = 0.f, s21 = 0.f, s30 = 0.f, s31 = 0.f;
        #pragma unroll
        for (int cs = 0; cs < 16; ++cs) {
            float4 xv0 = *(const float4*)&xsT[h0 * 68 + cs * 4];
            float4 xv1 = *(const float4*)&xsT[(h0 + 1) * 68 + cs * 4];
            float4 c0 = *(const float4*)&cws[(o0 + 0) * 64 + cs * 4];
            float4 c1 = *(const float4*)&cws[(o0 + 1) * 64 + cs * 4];
            float4 c2 = *(const float4*)&cws[(o0 + 2) * 64 + cs * 4];
            float4 c3 = *(const float4*)&cws[(o0 + 3) * 64 + cs * 4];
            s00 += dot4(xv0, c0); s01 += dot4(xv1, c0);
            s10 += dot4(xv0, c1); s11 += dot4(xv1, c1);
            s20 += dot4(xv0, c2); s21 += dot4(xv1, c2);
            s30 += dot4(xv0, c3); s31 += dot4(xv1, c3);
        }
        #pragma unroll
        for (int qq = 0; qq < 4; ++qq) {
            #pragma unroll
            for (int hh = 0; hh < 2; ++hh) {
                float sv = (qq == 0) ? (hh ? s01 : s00)
                         : (qq == 1) ? (hh ? s11 : s10)
                         : (qq == 2) ? (hh ? s21 : s20)
                                     : (hh ? s31 : s30);
                int o = o0 + qq, h = h0 + hh;
                float val = sv * inv_s * gs[o] + bt[o];
                int j = o * 56 + h;
                qkv[b * 5376 + j] = val;
                int f = j % 96;                  // raw (B,96,56)->(B,56,96)
                if (f < 32) wm[(j / 96) * 32 + f] = val;
            }
        }
    }
    __syncthreads();
    if (tid < 224) {
        int u = tid / 56, t = tid % 56;
        float s = 0.f;
        #pragma unroll 8
        for (int f = 0; f < 32; ++f) s += wm[t * 32 + f] * rl[f * 4 + u];
        code[tid] = ((s < 0.f) ? 1 : 0) + 2 * u;
    }
    __syncthreads();
    if (tid < 224) {
        int c = code[tid], r = 0;
        #pragma unroll 8
        for (int p = 0; p < 224; ++p) {
            int cp = code[p];
            r += (int)((cp < c) | ((cp == c) & (p < tid)));  // stable rank
        }
        srt[r] = tid;
    }
    __syncthreads();
    if (tid < 224) idx_buf[b * 224 + tid] = srt[tid];
}

// ---------------- K3: chunked attention, one block per (b,u), ALL 3 k's ----
// Stage once (gather+normalize+nrm), DI for 3 k's (ROLLED kq), fold, main
// x3 k's with reconstructed wbr. Rolled loops everywhere = spill brake.
// LDS 56.0KB -> 2 blocks/CU; 448 blocks = single resident round (no tail).
__global__ __launch_bounds__(512) void k3_attn(
        const float* __restrict__ qkv, const int* __restrict__ idx_buf,
        const float* __restrict__ rel, float* __restrict__ Rb,
        float* __restrict__ bsb) {
    __shared__ __align__(16) float Wc[8][3][25][4];   // normalized, then folded
    __shared__ __align__(16) float Vb[8][3][25][8];
    __shared__ float nrm[8][3][25];                   // |v| per (g,kk,i)
    __shared__ float DIT[3][75][25];                  // di*LOG2E; ibL aliases
    __shared__ __align__(16) float weL[75][4];        // 0.1*we[j]
    __shared__ __align__(16) float veL[600];          // VE[j][0..7]
    int* ibL = (int*)&DIT[0][0][0];
    const int b = blockIdx.x, u = blockIdx.y;
    const int tid = threadIdx.x;
    const float* q = qkv + b * 5376;

    if (tid < 224) ibL[tid] = idx_buf[b * 224 + tid];
    for (int i2 = tid; i2 < 300; i2 += 512) {         // weL (prescaled 0.1x)
        int j = i2 >> 2, c = i2 & 3;
        int roww = (j < 56) ? j : j - 19;
        weL[j][c] = 0.1f * rel[roww * 12 + c];
    }
    #pragma unroll 2
    for (int i2 = tid; i2 < 600; i2 += 512) {         // veL
        int j = i2 >> 3, c = i2 & 7;
        int roww = (j < 56) ? j : j - 19;
        veL[i2] = rel[roww * 12 + 4 + c];
    }
    __syncthreads();

    // Gather + normalize (ONCE for all 3 k's); keep norms for reconstruction.
    #pragma unroll 2
    for (int idx = tid; idx < 600; idx += 512) {
        int i = idx % 25, kk = (idx / 25) % 3, g = idx / 75;
        int p0 = 1200 * g + 300 * u + 100 * kk + 4 * i;
        int h = p0 / 2400, r = p0 % 2400, t = r >> 5, f = r & 31;
        int row = (t < 56) ? t : t - 19;
        int tt = ibL[h * 56 + row] % 56;
        float4 v = *(const float4*)&q[tt * 96 + f];
        float len = fmaxf(sqrtf(dot4(v, v)), EPSN);
        float ni = 1.0f / len;
        v.x *= ni; v.y *= ni; v.z *= ni; v.w *= ni;
        *(float4*)&Wc[g][kk][i][0] = v;
        nrm[g][kk][i] = len;
    }
    #pragma unroll 3
    for (int idx = tid; idx < 1200; idx += 512) {
        int half = idx & 1, fr = idx >> 1;
        int i = fr % 25, kk = (fr / 25) % 3, g = fr / 75;
        int p0 = 2400 * g + 600 * u + 200 * kk + 8 * i + 4 * half;
        int h = p0 / 4800, r = p0 % 4800, t = r >> 6, f = r & 63;
        int row = (t < 56) ? t : t - 19;
        int tt = ibL[h * 56 + row] % 56;
        *(float4*)&Vb[g][kk][i][4 * half] = *(const float4*)&q[tt * 96 + 32 + f];
    }
    __syncthreads();                      // ibL dead; DIT writable

    // DI: 375 threads; kq loop ROLLED (one wb8[8] live at a time).
    if (tid < 375) {
        const int i = tid % 25, jg = tid / 25;        // jg 0..14
        #pragma unroll 1
        for (int kq = 0; kq < 3; ++kq) {
            float4 wb8[8];
            #pragma unroll
            for (int g = 0; g < 8; ++g) {
                float4 t4 = *(const float4*)&Wc[g][kq][i][0];
                float nr = nrm[g][kq][i];
                wb8[g].x = t4.x * nr; wb8[g].y = t4.y * nr;
                wb8[g].z = t4.z * nr; wb8[g].w = t4.w * nr;
            }
            #pragma unroll
            for (int it = 0; it < 5; ++it) {
                int j = jg * 5 + it;
                int ks = (j >= 25) + (j >= 50), jj = j - ks * 25;
                float4 we = *(const float4*)&weL[j][0];   // already 0.1x
                float s2 = 0.f;
                #pragma unroll
                for (int g = 0; g < 8; ++g) {
                    float4 wcn = *(const float4*)&Wc[g][ks][jj][0];
                    float raw = dot4(wb8[g], wcn);
                    float emb = dot4(wb8[g], we);
                    s2 += raw * raw + emb * emb;
                }
                DIT[kq][j][i] = fminf(__builtin_amdgcn_rsqf(s2), INV_EPSN) * LOG2E;
            }
        }
    }
    __syncthreads();

    // Fold 0.1*we into Wc (in place).
    #pragma unroll 2
    for (int idx = tid; idx < 600; idx += 512) {
        int i = idx % 25, kk = (idx / 25) % 3, g = idx / 75;
        float4 we = *(const float4*)&weL[kk * 25 + i][0];
        float4 v = *(const float4*)&Wc[g][kk][i][0];
        v.x += we.x; v.y += we.y; v.z += we.z; v.w += we.w;
        *(float4*)&Wc[g][kk][i][0] = v;
    }
    __syncthreads();

    // Main x3 k's: channel-split lane pairs, rolled j loop (unroll 5).
    if (tid < 400) {
        const int half = tid & 1, gi = tid >> 1;      // gi 0..199
        const int g = gi & 7, i = gi >> 3;
        const int co = 4 * half;
        const float* Wcf = &Wc[g][0][0][0];           // j-contig, stride 4
        const float* Vbf = &Vb[g][0][0][co];          // j-contig, stride 8
        const float* vef = &veL[co];                  // j-contig, stride 8
        #pragma unroll 1
        for (int kq = 0; kq < 3; ++kq) {
            float4 wbr;                               // reconstruct raw w_b
            {
                float4 t4 = *(const float4*)&Wc[g][kq][i][0];   // folded
                float4 wei = *(const float4*)&weL[kq * 25 + i][0];
                float nr = nrm[g][kq][i];
                wbr.x = (t4.x - wei.x) * nr;
                wbr.y = (t4.y - wei.y) * nr;
                wbr.z = (t4.z - wei.z) * nr;
                wbr.w = (t4.w - wei.w) * nr;
            }
            const float* DIf = &DIT[kq][0][i];        // j-contig, stride 25
            float se = 0.f;
            float4 av = {0,0,0,0}, ae = {0,0,0,0};
            #pragma unroll 5
            for (int j = 0; j < 75; ++j) {            // ROLLED: spill brake
                float e = __builtin_amdgcn_exp2f(
                    dot4(wbr, *(const float4*)&Wcf[j * 4]) * DIf[j * 25]);
                se += e;
                fma4(av, e, *(const float4*)&Vbf[j * 8]);
                fma4(ae, e, *(const float4*)&vef[j * 8]);
            }
            if (half == 0)
                bsb[b * 2400 + g * 300 + u * 75 + kq * 25 + i] =
                    __builtin_amdgcn_logf(se) * LN2;  // logsumexp, no shift
            const float rinv = 1.0f / se;
            const float r2 = 0.1f * rinv;             // F_GV1
            av.x *= rinv; av.y *= rinv; av.z *= rinv; av.w *= rinv;
            ae.x *= r2;   ae.y *= r2;   ae.z *= r2;   ae.w *= r2;
            float* rp = Rb + b * 38400 + 4800 * g + 1200 * u + 400 * kq + 16 * i;
            *(float4*)(rp + co) = av;                 // V half
            *(float4*)(rp + 8 + co) = ae;             // VE half
        }
    }
}

// ---------------- K45: channel l2norm + bs-pass + unsort + hash softmax
//                        + transposed FP32 store. Split (b, o-half), 512 thr.
__global__ __launch_bounds__(512) void k45_post(
        const float* __restrict__ Rb, const float* __restrict__ bsb,
        const int* __restrict__ idx_buf, float* __restrict__ out) {
    __shared__ float D[300];
    __shared__ float bsn[300];
    __shared__ float retU[224][32];
    __shared__ float bsU[224];
    __shared__ int idxL[224];
    const int b = blockIdx.x, oh = blockIdx.y, tid = threadIdx.x;
    const int n = b / 56, w = b % 56, o0 = oh * 32;
    const float* R = Rb + b * 38400;
    if (tid < 224) idxL[tid] = idx_buf[b * 224 + tid];
    if (tid < 300) {
        float s = 0.f;
        #pragma unroll 16
        for (int c = 0; c < 128; ++c) { float v = R[c * 300 + tid]; s += v * v; }
        D[tid] = fminf(__builtin_amdgcn_rsqf(s), INV_EPSN);
    }
    if (tid < 300) {
        int u = tid / 75, t = tid % 75;
        float s2 = 0.f, sum = 0.f;
        #pragma unroll
        for (int g = 0; g < 8; ++g) {
            float v = bsb[b * 2400 + g * 300 + u * 75 + t];
            s2 += v * v; sum += v;
        }
        bsn[tid] = sum / fmaxf(sqrtf(s2), EPSN);
    }
    __syncthreads();
    if (tid < 224) {
        int u3 = tid / 56, t = tid % 56;
        bsU[idxL[tid]] = bsn[u3 * 75 + t];
    }
    #pragma unroll 4
    for (int idx = tid; idx < 224 * 32; idx += 512) {
        int p = idx >> 5, oc = idx & 31;
        int o = o0 + oc;
        int u3 = p / 56, t = p % 56;
        int k3 = t / 25, i3 = t % 25;
        int q0 = 9600 * u3 + 3200 * k3 + 128 * i3 + 2 * o;
        float2 rv = *(const float2*)&R[q0];
        int r0 = q0 % 300;                       // q0 even => r0+1 never wraps
        float val = rv.x * D[r0] + rv.y * D[r0 + 1];
        retU[idxL[p]][oc] = val;
    }
    __syncthreads();
    for (int idx = tid; idx < 56 * 32; idx += 512) {
        int h = idx >> 5, oc = idx & 31;
        int o = o0 + oc;
        float b0 = bsU[h], b1 = bsU[56 + h], b2 = bsU[112 + h], b3 = bsU[168 + h];
        float m = fmaxf(fmaxf(b0, b1), fmaxf(b2, b3));
        float e0 = __builtin_amdgcn_exp2f((b0 - m) * LOG2E);
        float e1 = __builtin_amdgcn_exp2f((b1 - m) * LOG2E);
        float e2 = __builtin_amdgcn_exp2f((b2 - m) * LOG2E);
        float e3 = __builtin_amdgcn_exp2f((b3 - m) * LOG2E);
        float ps = e0 + e1 + e2 + e3;
        float val = (retU[h][oc] * e0 + retU[56 + h][oc] * e1 +
                     retU[112 + h][oc] * e2 + retU[168 + h][oc] * e3) / ps;
        out[((n * 64 + o) * 56 + h) * 56 + w] = val;   // (n,o,h,w)
    }
}

extern "C" void kernel_launch(void* const* d_in, const int* in_sizes, int n_in,
                              void* d_out, int out_size, void* d_ws, size_t ws_size,
                              hipStream_t stream) {
    (void)in_sizes; (void)n_in; (void)out_size; (void)ws_size;
    const float* x     = (const float*)d_in[0];
    const float* cw    = (const float*)d_in[1];
    const float* gamma = (const float*)d_in[2];
    const float* beta  = (const float*)d_in[3];
    const float* rel   = (const float*)d_in[4];
    const float* rot   = (const float*)d_in[5];
    float* ws  = (float*)d_ws;
    float* qkv = ws;
    float* bsb = ws + 602112;
    float* Rb  = ws + 870912;
    float* xT  = Rb;                 // aliases Rb; dead once k3 writes Rb
    int*   idx = (int*)(ws + 5171712);

    k0_xT<<<dim3(2, 56), 256, 0, stream>>>(x, xT);
    k12_qkv_sort<<<112, 256, 0, stream>>>(xT, cw, gamma, beta, rot, qkv, idx);
    k3_attn<<<dim3(112, 4), 512, 0, stream>>>(qkv, idx, rel, Rb, bsb);
    k45_post<<<dim3(112, 2), 512, 0, stream>>>(Rb, bsb, idx, (float*)d_out);
}

// Round 13
// 141.273 us; speedup vs baseline: 1.2895x; 1.0530x over previous
//
#include <hip/hip_runtime.h>
#include <math.h>

// ============================================================================
// Sizes (fixed): N=2, C=64, Hax=56, W=56 -> B=112, H=56, OUT=64, N_HASHES=4,
// CHUNK=25, GROUPS=8, GP=8, hash_buckets=2, padding=19, K=3, qkv ch=96.
// Inputs fp32; OUTPUT FP32; stable argsort (established R8-R11).
// R24: 142.3us, k3=49.4 @ VGPR40/LDS45.5K/3blk-CU (best k3 config).
// R26: K-merge concluded NET-NEGATIVE: 52.8us @ VGPR112/LDS57.3K/2blk-CU.
//      FETCH was 1.3MB in BOTH -> the 3x qkv re-gathers were L2 hits, never
//      HBM; merge saved instructions but paid 2.4x occupancy. Reverted.
// R27: k3 = R24 exact. k12: cws staging float4 (6144 scalar -> 1536 f4).
//      k45: D-pass grid-stride 600 tasks (rowxcol-half, 64 loads) over all
//      512 threads + Dp combine (was 300 thr x 128 loads on 5/8 waves).
//
// ws layout (float slots):
//   qkv : [112][5376]   off 0
//   bsb : [112][2400]   off 602112
//   Rb  : [112][38400]  off 870912  (xT[2][56][56][64] aliases this pre-k3)
//   idx : [112][224]    off 5171712 (int)
// ============================================================================

#define EPSN 5e-5f
#define INV_EPSN 20000.0f
#define LOG2E 1.4426950408889634f
#define LN2   0.6931471805599453f

__device__ __forceinline__ float dot4(const float4 a, const float4 b) {
    return a.x * b.x + a.y * b.y + a.z * b.z + a.w * b.w;
}
__device__ __forceinline__ void fma4(float4& a, float s, const float4 v) {
    a.x += s * v.x; a.y += s * v.y; a.z += s * v.z; a.w += s * v.w;
}

// ---------------- K0: x[n][c][h][w] -> xT[n][h][w][c] (LDS transpose) ------
__global__ __launch_bounds__(256) void k0_xT(
        const float* __restrict__ x, float* __restrict__ xT) {
    __shared__ float T[64][57];                 // pad 57: conflict-free read
    const int n = blockIdx.x, h = blockIdx.y, tid = threadIdx.x;
    const float* xb = x + n * 200704 + h * 56;
    #pragma unroll 7
    for (int i = tid; i < 3584; i += 256) {     // lanes: consecutive w
        int c = i / 56, w = i % 56;
        T[c][w] = xb[c * 3136 + w];
    }
    __syncthreads();
    float* xo = xT + n * 200704 + h * 3584;
    #pragma unroll 7
    for (int i = tid; i < 3584; i += 256) {     // lanes: consecutive c
        int w = i / 64, c = i % 64;
        xo[w * 64 + c] = T[c][w];
    }
}

// ---------------- K12: qkv GEMM + BN + LSH codes + stable argsort ----------
// o-quad x h-pair register tile: 672 tiles, 6 LDS reads per 32 FMA.
__global__ __launch_bounds__(256) void k12_qkv_sort(
        const float* __restrict__ xT, const float* __restrict__ cw,
        const float* __restrict__ gamma, const float* __restrict__ beta,
        const float* __restrict__ rot, float* __restrict__ qkv,
        int* __restrict__ idx_buf) {
    __shared__ float xsT[56 * 68];   // [h][c], pad 64->68
    __shared__ __align__(16) float cws[96 * 64];
    __shared__ float wm[56 * 32];    // w_match[t][f]
    __shared__ float rl[128];
    __shared__ float gs[96], bt[96];
    __shared__ int code[224];
    __shared__ int srt[224];
    const int b = blockIdx.x, n = b / 56, w = b % 56, tid = threadIdx.x;
    const float* xTb = xT + n * 200704 + w * 64;
    #pragma unroll 4
    for (int i = tid; i < 896; i += 256) {      // coalesced float4 rows
        int h = i / 16, cq = i % 16;
        *(float4*)&xsT[h * 68 + cq * 4] =
            *(const float4*)&xTb[h * 3584 + cq * 4];
    }
    const float4* cw4 = (const float4*)cw;      // 1536 float4 loads (was 6144)
    #pragma unroll 2
    for (int i = tid; i < 1536; i += 256) ((float4*)cws)[i] = cw4[i];
    if (tid < 128) rl[tid] = rot[tid];
    if (tid < 96) { gs[tid] = gamma[tid]; bt[tid] = beta[tid]; }
    __syncthreads();
    const float inv_s = 1.0f / sqrtf(1.0f + 1.0e-5f);
    // 672 tiles = 24 o-quads x 28 h-pairs.
    for (int tl = tid; tl < 672; tl += 256) {
        int oq = tl / 28, hp = tl % 28;
        int o0 = oq * 4, h0 = hp * 2;
        float s00 = 0.f, s01 = 0.f, s10 = 0.f, s11 = 0.f;
        float s20 = 0.f, s21 = 0.f, s30 = 0.f, s31 = 0.f;
        #pragma unroll
        for (int cs = 0; cs < 16; ++cs) {
            float4 xv0 = *(const float4*)&xsT[h0 * 68 + cs * 4];
            float4 xv1 = *(const float4*)&xsT[(h0 + 1) * 68 + cs * 4];
            float4 c0 = *(const float4*)&cws[(o0 + 0) * 64 + cs * 4];
            float4 c1 = *(const float4*)&cws[(o0 + 1) * 64 + cs * 4];
            float4 c2 = *(const float4*)&cws[(o0 + 2) * 64 + cs * 4];
            float4 c3 = *(const float4*)&cws[(o0 + 3) * 64 + cs * 4];
            s00 += dot4(xv0, c0); s01 += dot4(xv1, c0);
            s10 += dot4(xv0, c1); s11 += dot4(xv1, c1);
            s20 += dot4(xv0, c2); s21 += dot4(xv1, c2);
            s30 += dot4(xv0, c3); s31 += dot4(xv1, c3);
        }
        #pragma unroll
        for (int qq = 0; qq < 4; ++qq) {
            #pragma unroll
            for (int hh = 0; hh < 2; ++hh) {
                float sv = (qq == 0) ? (hh ? s01 : s00)
                         : (qq == 1) ? (hh ? s11 : s10)
                         : (qq == 2) ? (hh ? s21 : s20)
                                     : (hh ? s31 : s30);
                int o = o0 + qq, h = h0 + hh;
                float val = sv * inv_s * gs[o] + bt[o];
                int j = o * 56 + h;
                qkv[b * 5376 + j] = val;
                int f = j % 96;                  // raw (B,96,56)->(B,56,96)
                if (f < 32) wm[(j / 96) * 32 + f] = val;
            }
        }
    }
    __syncthreads();
    if (tid < 224) {
        int u = tid / 56, t = tid % 56;
        float s = 0.f;
        #pragma unroll 8
        for (int f = 0; f < 32; ++f) s += wm[t * 32 + f] * rl[f * 4 + u];
        code[tid] = ((s < 0.f) ? 1 : 0) + 2 * u;
    }
    __syncthreads();
    if (tid < 224) {
        int c = code[tid], r = 0;
        #pragma unroll 8
        for (int p = 0; p < 224; ++p) {
            int cp = code[p];
            r += (int)((cp < c) | ((cp == c) & (p < tid)));  // stable rank
        }
        srt[r] = tid;
    }
    __syncthreads();
    if (tid < 224) idx_buf[b * 224 + tid] = srt[tid];
}

// ---------------- K3: chunked attention, one block per (b,u,k), 512 thr ----
// R24 exact: rolled runtime-j main loop (unroll 5), linearized LDS
// addressing, channel split across lane pairs. LDS 45.5KB -> 3 blocks/CU.
__global__ __launch_bounds__(512) void k3_attn(
        const float* __restrict__ qkv, const int* __restrict__ idx_buf,
        const float* __restrict__ rel, float* __restrict__ Rb,
        float* __restrict__ bsb) {
    __shared__ __align__(16) float Wc[8][3][25][4];   // normalized, then +0.1*we
    __shared__ __align__(16) float Vb[8][3][25][8];
    __shared__ __align__(16) float WbK[8][25][4];     // raw w_b at kk==k
    __shared__ float DIT[75][25];                     // di * LOG2E, transposed
    __shared__ __align__(16) float relL[672];         // rel[56][12] staged
    __shared__ __align__(16) float veL[600];          // VE[j][0..7], j-indexed
    __shared__ int ibL[224];
    const int b = blockIdx.x, u = blockIdx.y, k = blockIdx.z;
    const int tid = threadIdx.x;
    const float* q = qkv + b * 5376;

    if (tid < 224) ibL[tid] = idx_buf[b * 224 + tid];
    for (int i2 = tid; i2 < 672; i2 += 512) relL[i2] = rel[i2];
    // veL[j*8+c] = rel[roww(j)*12 + 4 + c]
    #pragma unroll 2
    for (int i2 = tid; i2 < 600; i2 += 512) {
        int j = i2 >> 3, c = i2 & 7;
        int roww = (j < 56) ? j : j - 19;
        veL[i2] = rel[roww * 12 + 4 + c];
    }
    __syncthreads();

    #pragma unroll 2
    for (int idx = tid; idx < 600; idx += 512) {
        int i = idx % 25, kk = (idx / 25) % 3, g = idx / 75;
        int p0 = 1200 * g + 300 * u + 100 * kk + 4 * i;
        int h = p0 / 2400, r = p0 % 2400, t = r >> 5, f = r & 31;
        int row = (t < 56) ? t : t - 19;
        int tt = ibL[h * 56 + row] % 56;
        float4 v = *(const float4*)&q[tt * 96 + f];
        if (kk == k) *(float4*)&WbK[g][i][0] = v;
        float ni = fminf(__builtin_amdgcn_rsqf(dot4(v, v)), INV_EPSN);
        v.x *= ni; v.y *= ni; v.z *= ni; v.w *= ni;
        *(float4*)&Wc[g][kk][i][0] = v;
    }
    #pragma unroll 3
    for (int idx = tid; idx < 1200; idx += 512) {
        int half = idx & 1, fr = idx >> 1;
        int i = fr % 25, kk = (fr / 25) % 3, g = fr / 75;
        int p0 = 2400 * g + 600 * u + 200 * kk + 8 * i + 4 * half;
        int h = p0 / 4800, r = p0 % 4800, t = r >> 6, f = r & 63;
        int row = (t < 56) ? t : t - 19;
        int tt = ibL[h * 56 + row] % 56;
        *(float4*)&Vb[g][kk][i][4 * half] = *(const float4*)&q[tt * 96 + 32 + f];
    }
    __syncthreads();

    // DI phase: 375 threads x 5 j's; register wb8; DIT[j][i] = di*LOG2E.
    if (tid < 375) {
        const int i = tid % 25, jg = tid / 25;    // jg 0..14
        float4 wb8[8];
        #pragma unroll
        for (int g = 0; g < 8; ++g) wb8[g] = *(const float4*)&WbK[g][i][0];
        #pragma unroll
        for (int it = 0; it < 5; ++it) {
            int j = jg * 5 + it;
            int ks = (j >= 25) + (j >= 50), jj = j - ks * 25;
            int roww = (j < 56) ? j : j - 19;
            float4 we = *(const float4*)&relL[roww * 12];
            we.x *= 0.1f; we.y *= 0.1f; we.z *= 0.1f; we.w *= 0.1f;
            float s2 = 0.f;
            #pragma unroll
            for (int g = 0; g < 8; ++g) {
                float4 wcn = *(const float4*)&Wc[g][ks][jj][0];
                float raw = dot4(wb8[g], wcn);
                float emb = dot4(wb8[g], we);
                s2 += raw * raw + emb * emb;
            }
            DIT[j][i] = fminf(__builtin_amdgcn_rsqf(s2), INV_EPSN) * LOG2E;
        }
    }
    __syncthreads();

    // Fold 0.1*we into Wc so main loop is one dot4 per (g,j).
    #pragma unroll 2
    for (int idx = tid; idx < 600; idx += 512) {
        int i = idx % 25, kk = (idx / 25) % 3, g = idx / 75;
        int tw = kk * 25 + i;
        int roww = (tw < 56) ? tw : tw - 19;
        float4 we = *(const float4*)&relL[roww * 12];
        float4 v = *(const float4*)&Wc[g][kk][i][0];
        v.x += 0.1f * we.x; v.y += 0.1f * we.y;
        v.z += 0.1f * we.z; v.w += 0.1f * we.w;
        *(float4*)&Wc[g][kk][i][0] = v;
    }
    __syncthreads();

    // Main: pair lanes (2p,2p+1) identical runtime j; lane owns channel half.
    if (tid < 400) {
        const int half = tid & 1, gi = tid >> 1;  // gi 0..199
        const int g = gi & 7, i = gi >> 3;
        const int co = 4 * half;                  // channel-half offset
        const float4 wbr = *(const float4*)&WbK[g][i][0];
        const float* Wcf = &Wc[g][0][0][0];       // j-contiguous, stride 4
        const float* Vbf = &Vb[g][0][0][co];      // j-contiguous, stride 8
        const float* vef = &veL[co];              // j-contiguous, stride 8
        const float* DIf = &DIT[0][i];            // j-contiguous, stride 25
        float se = 0.f;
        float4 av = {0,0,0,0}, ae = {0,0,0,0};
        #pragma unroll 5
        for (int j = 0; j < 75; ++j) {            // ROLLED: the spill brake
            float e = __builtin_amdgcn_exp2f(
                dot4(wbr, *(const float4*)&Wcf[j * 4]) * DIf[j * 25]);
            se += e;
            fma4(av, e, *(const float4*)&Vbf[j * 8]);
            fma4(ae, e, *(const float4*)&vef[j * 8]);
        }
        if (half == 0)
            bsb[b * 2400 + g * 300 + u * 75 + k * 25 + i] =
                __builtin_amdgcn_logf(se) * LN2;              // logsumexp
        const float rinv = 1.0f / se;
        const float r2 = 0.1f * rinv;                         // F_GV1
        av.x *= rinv; av.y *= rinv; av.z *= rinv; av.w *= rinv;
        ae.x *= r2;   ae.y *= r2;   ae.z *= r2;   ae.w *= r2;
        float* rp = Rb + b * 38400 + 4800 * g + 1200 * u + 400 * k + 16 * i;
        *(float4*)(rp + co) = av;             // V half   -> rp[0]/rp[1]
        *(float4*)(rp + 8 + co) = ae;         // VE half  -> rp[2]/rp[3]
    }
}

// ---------------- K45: channel l2norm + bs-pass + unsort + hash softmax
//                        + transposed FP32 store. Split (b, o-half), 512 thr.
// D-pass: grid-stride 600 (row x col-half) tasks over 512 threads + combine.
__global__ __launch_bounds__(512) void k45_post(
        const float* __restrict__ Rb, const float* __restrict__ bsb,
        const int* __restrict__ idx_buf, float* __restrict__ out) {
    __shared__ float Dp[600];
    __shared__ float D[300];
    __shared__ float bsn[300];
    __shared__ float retU[224][32];
    __shared__ float bsU[224];
    __shared__ int idxL[224];
    const int b = blockIdx.x, oh = blockIdx.y, tid = threadIdx.x;
    const int n = b / 56, w = b % 56, o0 = oh * 32;
    const float* R = Rb + b * 38400;
    if (tid < 224) idxL[tid] = idx_buf[b * 224 + tid];
    #pragma unroll 1
    for (int task = tid; task < 600; task += 512) {
        int r = task % 300, half = task / 300;
        const float* Rc = R + half * 64 * 300 + r;
        float s = 0.f;
        #pragma unroll 16
        for (int c = 0; c < 64; ++c) { float v = Rc[c * 300]; s += v * v; }
        Dp[task] = s;
    }
    if (tid < 300) {
        int u = tid / 75, t = tid % 75;
        float s2 = 0.f, sum = 0.f;
        #pragma unroll
        for (int g = 0; g < 8; ++g) {
            float v = bsb[b * 2400 + g * 300 + u * 75 + t];
            s2 += v * v; sum += v;
        }
        bsn[tid] = sum / fmaxf(sqrtf(s2), EPSN);
    }
    __syncthreads();                             // Dp, bsn ready
    if (tid < 300)
        D[tid] = fminf(__builtin_amdgcn_rsqf(Dp[tid] + Dp[tid + 300]), INV_EPSN);
    if (tid < 224) {
        int u3 = tid / 56, t = tid % 56;
        bsU[idxL[tid]] = bsn[u3 * 75 + t];
    }
    __syncthreads();                             // D, bsU ready
    #pragma unroll 4
    for (int idx = tid; idx < 224 * 32; idx += 512) {
        int p = idx >> 5, oc = idx & 31;
        int o = o0 + oc;
        int u3 = p / 56, t = p % 56;
        int k3 = t / 25, i3 = t % 25;
        int q0 = 9600 * u3 + 3200 * k3 + 128 * i3 + 2 * o;
        float2 rv = *(const float2*)&R[q0];
        int r0 = q0 % 300;                       // q0 even => r0+1 never wraps
        float val = rv.x * D[r0] + rv.y * D[r0 + 1];
        retU[idxL[p]][oc] = val;
    }
    __syncthreads();
    for (int idx = tid; idx < 56 * 32; idx += 512) {
        int h = idx >> 5, oc = idx & 31;
        int o = o0 + oc;
        float b0 = bsU[h], b1 = bsU[56 + h], b2 = bsU[112 + h], b3 = bsU[168 + h];
        float m = fmaxf(fmaxf(b0, b1), fmaxf(b2, b3));
        float e0 = __builtin_amdgcn_exp2f((b0 - m) * LOG2E);
        float e1 = __builtin_amdgcn_exp2f((b1 - m) * LOG2E);
        float e2 = __builtin_amdgcn_exp2f((b2 - m) * LOG2E);
        float e3 = __builtin_amdgcn_exp2f((b3 - m) * LOG2E);
        float ps = e0 + e1 + e2 + e3;
        float val = (retU[h][oc] * e0 + retU[56 + h][oc] * e1 +
                     retU[112 + h][oc] * e2 + retU[168 + h][oc] * e3) / ps;
        out[((n * 64 + o) * 56 + h) * 56 + w] = val;   // (n,o,h,w)
    }
}

extern "C" void kernel_launch(void* const* d_in, const int* in_sizes, int n_in,
                              void* d_out, int out_size, void* d_ws, size_t ws_size,
                              hipStream_t stream) {
    (void)in_sizes; (void)n_in; (void)out_size; (void)ws_size;
    const float* x     = (const float*)d_in[0];
    const float* cw    = (const float*)d_in[1];
    const float* gamma = (const float*)d_in[2];
    const float* beta  = (const float*)d_in[3];
    const float* rel   = (const float*)d_in[4];
    const float* rot   = (const float*)d_in[5];
    float* ws  = (float*)d_ws;
    float* qkv = ws;
    float* bsb = ws + 602112;
    float* Rb  = ws + 870912;
    float* xT  = Rb;                 // aliases Rb; dead once k3 writes Rb
    int*   idx = (int*)(ws + 5171712);

    k0_xT<<<dim3(2, 56), 256, 0, stream>>>(x, xT);
    k12_qkv_sort<<<112, 256, 0, stream>>>(xT, cw, gamma, beta, rot, qkv, idx);
    k3_attn<<<dim3(112, 4, 3), 512, 0, stream>>>(qkv, idx, rel, Rb, bsb);
    k45_post<<<dim3(112, 2), 512, 0, stream>>>(Rb, bsb, idx, (float*)d_out);
}